// Round 2
// baseline (6529.610 us; speedup 1.0000x reference)
//
#include <hip/hip_runtime.h>
#include <cstdint>

// LSTM fused kernel for MI355X — round 4: two-batch stagger.
// 32 blocks x 1024 threads; each block runs TWO independent batch recurrences
// offset by half a step. While batch A's 1024x256 int8 GEMV (issue-heavy) runs
// in all 16 waves, batch B's nonlinearity/quant/publish (latency-heavy) runs
// in its 4 owner waves — the two serial spines overlap. Weights (int8, VGPR)
// are shared by both batches; the 68-SGPR h-record set is time-shared
// (one batch per half-step). fc(t-1) sits inside the h-record K$-miss window
// so its forced lgkmcnt(0) IS the h wait. Per-batch math identical to the
// 3528us round-2 kernel (absmax-verified ops only).

#define B_  64
#define T_  2048
#define I_  32
#define H_  256
#define G4  1024
#define O_  32

typedef int v16i __attribute__((ext_vector_type(16)));
typedef int v4i  __attribute__((ext_vector_type(4)));
typedef unsigned int v4u __attribute__((ext_vector_type(4)));
typedef _Float16 h2_t __attribute__((ext_vector_type(2)));

#if __has_builtin(__builtin_amdgcn_sdot4)
__device__ __forceinline__ int dot4(int a, int b, int c) {
    return __builtin_amdgcn_sdot4(a, b, c, false);
}
#else
__device__ __forceinline__ int dot4(int a, int b, int c) {
    c += (int)(int8_t)(a)        * (int)(int8_t)(b);
    c += (int)(int8_t)(a >> 8)   * (int)(int8_t)(b >> 8);
    c += (int)(int8_t)(a >> 16)  * (int)(int8_t)(b >> 16);
    c += (int)(int8_t)(a >> 24)  * (int)(int8_t)(b >> 24);
    return c;
}
#endif

__device__ __forceinline__ float fdot2h(h2_t a, h2_t b, float c) {
#if __has_builtin(__builtin_amdgcn_fdot2)
    return __builtin_amdgcn_fdot2(a, b, c, false);
#else
    return c + (float)a[0] * (float)b[0] + (float)a[1] * (float)b[1];
#endif
}

// ---- DPP cross-lane reductions (VALU pipe; keep lgkm clean) ----
__device__ __forceinline__ float wave64_max_bcast(float v) {
    int t;
    t = __builtin_amdgcn_update_dpp(__float_as_int(v), __float_as_int(v), 0x111, 0xf, 0xf, false);
    v = fmaxf(v, __int_as_float(t));
    t = __builtin_amdgcn_update_dpp(__float_as_int(v), __float_as_int(v), 0x112, 0xf, 0xf, false);
    v = fmaxf(v, __int_as_float(t));
    t = __builtin_amdgcn_update_dpp(__float_as_int(v), __float_as_int(v), 0x114, 0xf, 0xf, false);
    v = fmaxf(v, __int_as_float(t));
    t = __builtin_amdgcn_update_dpp(__float_as_int(v), __float_as_int(v), 0x118, 0xf, 0xf, false);
    v = fmaxf(v, __int_as_float(t));
    t = __builtin_amdgcn_update_dpp(__float_as_int(v), __float_as_int(v), 0x142, 0xa, 0xf, false);
    v = fmaxf(v, __int_as_float(t));
    t = __builtin_amdgcn_update_dpp(__float_as_int(v), __float_as_int(v), 0x143, 0xc, 0xf, false);
    v = fmaxf(v, __int_as_float(t));
    return __int_as_float(__builtin_amdgcn_readlane(__float_as_int(v), 63));
}

// sum within each 32-lane half; lane31 holds sum(0..31), lane63 sum(32..63).
__device__ __forceinline__ float halfwave_sum31(float v) {
    int t;
    t = __builtin_amdgcn_update_dpp(0, __float_as_int(v), 0x111, 0xf, 0xf, true); v += __int_as_float(t);
    t = __builtin_amdgcn_update_dpp(0, __float_as_int(v), 0x112, 0xf, 0xf, true); v += __int_as_float(t);
    t = __builtin_amdgcn_update_dpp(0, __float_as_int(v), 0x114, 0xf, 0xf, true); v += __int_as_float(t);
    t = __builtin_amdgcn_update_dpp(0, __float_as_int(v), 0x118, 0xf, 0xf, true); v += __int_as_float(t);
    t = __builtin_amdgcn_update_dpp(0, __float_as_int(v), 0x142, 0xa, 0xf, true); v += __int_as_float(t);
    return v;
}

// ---------------- ws layout (all 256-B aligned) ----------------
#define QWHH_OFF 0
#define QWIH_OFF 262144
#define S1_OFF   327680
#define S2_OFF   331776
#define BIAS_OFF 335872
#define XQ_OFF   339968
#define XS_OFF   8728576
#define HBUF_OFF 9252864
#define HREC_STRIDE 320
#define HSLOTS 2049

__device__ __forceinline__ uint32_t pack_q(int q0, int q1, int q2, int q3) {
    return  ((uint32_t)(uint8_t)(int8_t)q0)
          | (((uint32_t)(uint8_t)(int8_t)q1) << 8)
          | (((uint32_t)(uint8_t)(int8_t)q2) << 16)
          | (((uint32_t)(uint8_t)(int8_t)q3) << 24);
}

__device__ __forceinline__ int clamp127(int v) {
    return v < -127 ? -127 : (v > 127 ? 127 : v);
}

// -------- prep: quantize weights (1 block of 64 thr per gate-row) --------
__global__ __launch_bounds__(64) void prep_w(
    const float* __restrict__ Whh, const float* __restrict__ Wih,
    const float* __restrict__ bih, const float* __restrict__ bhh,
    uint32_t* __restrict__ qwhh, uint32_t* __restrict__ qwih,
    float* __restrict__ s1, float* __restrict__ s2, float* __restrict__ bias)
{
    const int r = blockIdx.x;
    const int l = threadIdx.x;

    const float4 wv = ((const float4*)(Whh + r * H_))[l];
    float m = fmaxf(fmaxf(fabsf(wv.x), fabsf(wv.y)), fmaxf(fabsf(wv.z), fabsf(wv.w)));
    #pragma unroll
    for (int s = 1; s < 64; s <<= 1) m = fmaxf(m, __shfl_xor(m, s, 64));
    const float S1 = fmaxf(m, 1e-20f) / 127.f;

    float xm = (l < I_) ? fabsf(Wih[r * I_ + l]) : 0.f;
    #pragma unroll
    for (int s = 1; s < 64; s <<= 1) xm = fmaxf(xm, __shfl_xor(xm, s, 64));
    const float S2 = fmaxf(xm, 1e-20f) / 127.f;

    {
        const float r1 = 1.f / S1;
        qwhh[l * G4 + r] = pack_q(
            clamp127((int)rintf(wv.x * r1)), clamp127((int)rintf(wv.y * r1)),
            clamp127((int)rintf(wv.z * r1)), clamp127((int)rintf(wv.w * r1)));
    }
    if (l < 8) {
        const float4 xw = ((const float4*)(Wih + r * I_))[l];
        const float r2 = 1.f / S2;
        qwih[l * G4 + r] = pack_q(
            clamp127((int)rintf(xw.x * r2)), clamp127((int)rintf(xw.y * r2)),
            clamp127((int)rintf(xw.z * r2)), clamp127((int)rintf(xw.w * r2)));
    } else if (l < 16) {
        const int j = l - 8;
        const float4 xw = ((const float4*)(Wih + r * I_))[j];
        const float r2 = 1.f / S2;
        float v0 = xw.x * r2, v1 = xw.y * r2, v2 = xw.z * r2, v3 = xw.w * r2;
        int a0 = clamp127((int)rintf(v0)), a1 = clamp127((int)rintf(v1));
        int a2 = clamp127((int)rintf(v2)), a3 = clamp127((int)rintf(v3));
        qwih[(8 + j) * G4 + r] = pack_q(
            clamp127((int)rintf((v0 - (float)a0) * 127.f)),
            clamp127((int)rintf((v1 - (float)a1) * 127.f)),
            clamp127((int)rintf((v2 - (float)a2) * 127.f)),
            clamp127((int)rintf((v3 - (float)a3) * 127.f)));
    }
    if (l == 0) { s1[r] = S1; s2[r] = S2; bias[r] = bih[r] + bhh[r]; }
}

// -------- prep: quantize x (64 (b,t) rows per block) --------
__global__ __launch_bounds__(256) void prep_x(
    const float* __restrict__ x, uint32_t* __restrict__ xq, float* __restrict__ xs)
{
    __shared__ float xb[64 * 32];
    const int base = blockIdx.x * 64 * 32;
    for (int i = threadIdx.x; i < 2048; i += 256) xb[i] = x[base + i];
    __syncthreads();
    const int t = threadIdx.x;
    if (t < 64) {
        float m = 0.f;
        for (int k = 0; k < 32; k++) m = fmaxf(m, fabsf(xb[t * 32 + k]));
        const float S = fmaxf(m, 1e-20f) / 127.f;
        const int row = blockIdx.x * 64 + t;
        xs[row] = S;
        const float rS = 1.f / S;
        for (int j = 0; j < 8; j++) {
            int qa[4], qb[4];
            for (int e = 0; e < 4; e++) {
                float v = xb[t * 32 + j * 4 + e] * rS;
                int a = clamp127((int)rintf(v));
                int b = clamp127((int)rintf((v - (float)a) * 127.f));
                qa[e] = a; qb[e] = b;
            }
            xq[row * 16 + j]     = pack_q(qa[0], qa[1], qa[2], qa[3]);
            xq[row * 16 + 8 + j] = pack_q(qb[0], qb[1], qb[2], qb[3]);
        }
    }
}

// x contribution for one (b,t): scalar loads + int8 dots (hi/lo split)
__device__ __forceinline__ float x_contrib(const uint32_t* pxq, const float* pxs,
                                           const uint32_t* wA, const uint32_t* wB,
                                           float S2, float bias_r) {
    v16i xv; int sxi;
    asm volatile("s_load_dwordx16 %0, %2, 0x0\n\t"
                 "s_load_dword %1, %3, 0x0\n\t"
                 "s_waitcnt lgkmcnt(0)"
                 : "=&s"(xv), "=&s"(sxi)
                 : "s"(pxq), "s"(pxs)
                 : "memory");
    int aA = 0, aM = 0;
    #pragma unroll
    for (int j = 0; j < 8; j++) {
        aA = dot4((int)wA[j], xv[j],     aA);
        aM = dot4((int)wA[j], xv[8 + j], aM);
        aM = dot4((int)wB[j], xv[j],     aM);
    }
    return ((float)aA + (float)aM * (1.f / 127.f)) * (S2 * __int_as_float(sxi)) + bias_r;
}

// fc for one batch/timestep from an LDS f16 h-buffer (DPP reduce, lane31 stores)
__device__ __forceinline__ void fc_step(const uint32_t* hfbuf, float* outp, int trow,
                                        const h2_t* fw, float fcb_v, int o_, int kc) {
    const v4u hv = *(const v4u*)(&hfbuf[4 * kc]);
    union { uint32_t u; h2_t h; } u0, u1, u2, u3;
    u0.u = hv[0]; u1.u = hv[1]; u2.u = hv[2]; u3.u = hv[3];
    float acc = 0.f;
    acc = fdot2h(fw[0], u0.h, acc);
    acc = fdot2h(fw[1], u1.h, acc);
    acc = fdot2h(fw[2], u2.h, acc);
    acc = fdot2h(fw[3], u3.h, acc);
    acc = halfwave_sum31(acc);
    if (kc == 31) outp[trow * O_ + o_] = acc + fcb_v;
}

// -------- main: 2 batches per block, half-step staggered --------
__global__ __launch_bounds__(1024, 4) void lstm_main(
    const uint32_t* __restrict__ qwhh, const uint32_t* __restrict__ qwih,
    const float* __restrict__ s1v, const float* __restrict__ s2v,
    const float* __restrict__ biasv,
    const uint32_t* __restrict__ xq, const float* __restrict__ xs,
    const float* __restrict__ fcw, const float* __restrict__ fcb,
    char* __restrict__ hbuf, float* __restrict__ out)
{
    const int blk = blockIdx.x;
    const int b0  = 2 * blk, b1 = 2 * blk + 1;
    const int tid = threadIdx.x;

    __shared__ float    gbuf0[768];   // batch0: f,g,o  (rows 256..1023)
    __shared__ float    gbuf1[768];   // batch1: i,g,o  (rows 0..255, 512..1023)
    __shared__ uint32_t hf16a[128];   // batch0 h as f16 pairs
    __shared__ uint32_t hf16b[128];   // batch1 h as f16 pairs

    // resident int8 weights: row = tid (shared by both batches)
    uint32_t w[64], wA[8], wB[8];
    #pragma unroll
    for (int d = 0; d < 64; d++) w[d] = qwhh[d * G4 + tid];
    #pragma unroll
    for (int j = 0; j < 8; j++) { wA[j] = qwih[j * G4 + tid]; wB[j] = qwih[(8 + j) * G4 + tid]; }
    const float S1 = s1v[tid], S2 = s2v[tid], bias_r = biasv[tid];

    const int o_ = tid >> 5, kc = tid & 31;
    h2_t fw[4];
    {
        const float* fr = fcw + o_ * H_ + kc * 8;
        #pragma unroll
        for (int j = 0; j < 4; j++) {
            h2_t p; p[0] = (_Float16)fr[2 * j]; p[1] = (_Float16)fr[2 * j + 1];
            fw[j] = p;
        }
    }
    const float fcb_v = fcb[o_];

    char* hb0 = hbuf + (size_t)b0 * (HSLOTS * HREC_STRIDE);
    char* hb1 = hbuf + (size_t)b1 * (HSLOTS * HREC_STRIDE);
    {   // init zero-state records (slot 2048) for both batches
        char* z0 = hb0 + 2048 * HREC_STRIDE;
        char* z1 = hb1 + 2048 * HREC_STRIDE;
        if (tid < 256)      z0[tid] = 0;
        else if (tid < 512) z1[tid - 256] = 0;
        else if (tid < 516) ((float*)(z0 + 256))[tid - 512] = 0.f;
        else if (tid < 520) ((float*)(z1 + 256))[tid - 516] = 0.f;
    }

    const uint32_t* xq0 = xq + (size_t)(b0 * T_) * 16;
    const float*    xs0 = xs + (size_t)(b0 * T_);
    const uint32_t* xq1 = xq + (size_t)(b1 * T_) * 16;
    const float*    xs1 = xs + (size_t)(b1 * T_);
    float* out0 = out + (size_t)(b0 * T_) * O_;
    float* out1 = out + (size_t)(b1 * T_) * O_;

    float c_state = 0.f;            // c0 for tid<256, c1 for 256<=tid<512
    float gate0 = 0.f, gate1 = 0.f; // live across halves
    float xp0, xp1;

    xp0 = x_contrib(xq0, xs0, wA, wB, S2, bias_r);   // batch0, t=0

    __syncthreads();  // drain zero-record stores

    for (int t = 0; t < T_; t++) {
        // ======== HALF A: gates b0 @ t ; nonlin b1 @ t-1 ; fc b0 @ t-1 ========
        {
            const uint32_t slot = (t == 0) ? 2048u : ((uint32_t)(t * 1993) & 2047u);
            const char* hrec = hb0 + (size_t)slot * HREC_STRIDE;
            v16i h0, h1, h2, h3; v4i scv;
            asm volatile("s_load_dwordx16 %0, %5, 0x0\n\t"
                         "s_load_dwordx16 %1, %5, 0x40\n\t"
                         "s_load_dwordx16 %2, %5, 0x80\n\t"
                         "s_load_dwordx16 %3, %5, 0xc0\n\t"
                         "s_load_dwordx4  %4, %5, 0x100"
                         : "=&s"(h0), "=&s"(h1), "=&s"(h2), "=&s"(h3), "=&s"(scv)
                         : "s"(hrec)
                         : "memory");

            if (t > 0)   // fc b0 @ t-1 — its LDS-read wait merges with h-load stall
                fc_step(hf16a, out0, t - 1, fw, fcb_v, o_, kc);

            asm volatile("s_waitcnt lgkmcnt(0)"
                         : "+s"(h0), "+s"(h1), "+s"(h2), "+s"(h3), "+s"(scv)
                         :
                         : "memory");

            int a0 = 0, a1 = 0, a2 = 0, a3 = 0;
            #pragma unroll
            for (int d = 0; d < 16; d++) {
                a0 = dot4((int)w[d],      h0[d], a0);
                a1 = dot4((int)w[16 + d], h1[d], a1);
                a2 = dot4((int)w[32 + d], h2[d], a2);
                a3 = dot4((int)w[48 + d], h3[d], a3);
            }
            const float hsum = (float)a0 * __int_as_float(scv[0])
                             + (float)a1 * __int_as_float(scv[1])
                             + (float)a2 * __int_as_float(scv[2])
                             + (float)a3 * __int_as_float(scv[3]);
            gate0 = hsum * S1 + xp0;

            if (tid >= 256) gbuf0[tid - 256] = gate0;

            if (t > 0 && tid >= 256 && tid < 512) {   // nonlin b1 @ t-1
                const int rr = tid - 256;
                const float gi = gbuf1[rr];
                const float gf = gate1;               // own row's f-gate from HALF B
                const float gg = gbuf1[256 + rr];
                const float go = gbuf1[512 + rr];
                const float i_ = 1.f / (1.f + __expf(-gi));
                const float f_ = 1.f / (1.f + __expf(-gf));
                const float g_ = 2.f / (1.f + __expf(-2.f * gg)) - 1.f;
                const float oo = 1.f / (1.f + __expf(-go));
                c_state = f_ * c_state + i_ * g_;
                const float tc = 2.f / (1.f + __expf(-2.f * c_state)) - 1.f;
                const float hval = oo * tc;
                ((_Float16*)hf16b)[rr] = (_Float16)hval;

                float m = wave64_max_bcast(fabsf(hval));
                m = fmaxf(m, 1e-12f);
                const int q = clamp127((int)rintf(hval * (127.f / m)));
                char* hw = hb1 + (size_t)((uint32_t)(t * 1993) & 2047u) * HREC_STRIDE;
                hw[rr] = (char)(int8_t)q;
                if ((rr & 63) == 0)
                    ((float*)(hw + 256))[rr >> 6] = m * (1.f / 127.f);
            }

            xp1 = x_contrib(xq1 + (size_t)t * 16, xs1 + t, wA, wB, S2, bias_r);

            __syncthreads();   // publishes gbuf0, hf16b; drains b1 h stores
        }
        // ======== HALF B: gates b1 @ t ; nonlin b0 @ t ; fc b1 @ t-1 ========
        {
            const uint32_t slot = (t == 0) ? 2048u : ((uint32_t)(t * 1993) & 2047u);
            const char* hrec = hb1 + (size_t)slot * HREC_STRIDE;
            v16i h0, h1, h2, h3; v4i scv;
            asm volatile("s_load_dwordx16 %0, %5, 0x0\n\t"
                         "s_load_dwordx16 %1, %5, 0x40\n\t"
                         "s_load_dwordx16 %2, %5, 0x80\n\t"
                         "s_load_dwordx16 %3, %5, 0xc0\n\t"
                         "s_load_dwordx4  %4, %5, 0x100"
                         : "=&s"(h0), "=&s"(h1), "=&s"(h2), "=&s"(h3), "=&s"(scv)
                         : "s"(hrec)
                         : "memory");

            if (t > 0)   // fc b1 @ t-1
                fc_step(hf16b, out1, t - 1, fw, fcb_v, o_, kc);

            asm volatile("s_waitcnt lgkmcnt(0)"
                         : "+s"(h0), "+s"(h1), "+s"(h2), "+s"(h3), "+s"(scv)
                         :
                         : "memory");

            int a0 = 0, a1 = 0, a2 = 0, a3 = 0;
            #pragma unroll
            for (int d = 0; d < 16; d++) {
                a0 = dot4((int)w[d],      h0[d], a0);
                a1 = dot4((int)w[16 + d], h1[d], a1);
                a2 = dot4((int)w[32 + d], h2[d], a2);
                a3 = dot4((int)w[48 + d], h3[d], a3);
            }
            const float hsum = (float)a0 * __int_as_float(scv[0])
                             + (float)a1 * __int_as_float(scv[1])
                             + (float)a2 * __int_as_float(scv[2])
                             + (float)a3 * __int_as_float(scv[3]);
            gate1 = hsum * S1 + xp1;

            if (tid < 256)       gbuf1[tid] = gate1;          // i rows 0..255
            else if (tid >= 512) gbuf1[tid - 256] = gate1;    // g,o rows 512..1023

            if (tid < 256) {   // nonlin b0 @ t
                const float gi = gate0;
                const float gf = gbuf0[tid];
                const float gg = gbuf0[256 + tid];
                const float go = gbuf0[512 + tid];
                const float i_ = 1.f / (1.f + __expf(-gi));
                const float f_ = 1.f / (1.f + __expf(-gf));
                const float g_ = 2.f / (1.f + __expf(-2.f * gg)) - 1.f;
                const float oo = 1.f / (1.f + __expf(-go));
                c_state = f_ * c_state + i_ * g_;
                const float tc = 2.f / (1.f + __expf(-2.f * c_state)) - 1.f;
                const float hval = oo * tc;
                ((_Float16*)hf16a)[tid] = (_Float16)hval;

                float m = wave64_max_bcast(fabsf(hval));
                m = fmaxf(m, 1e-12f);
                const int q = clamp127((int)rintf(hval * (127.f / m)));
                char* hw = hb0 + (size_t)((uint32_t)((t + 1) * 1993) & 2047u) * HREC_STRIDE;
                hw[tid] = (char)(int8_t)q;
                if ((tid & 63) == 0)
                    ((float*)(hw + 256))[tid >> 6] = m * (1.f / 127.f);
            }

            const int tn = (t + 1 < T_) ? (t + 1) : t;
            xp0 = x_contrib(xq0 + (size_t)tn * 16, xs0 + tn, wA, wB, S2, bias_r);

            __syncthreads();   // publishes gbuf1, hf16a; drains b0 h stores
        }
    }

    // ---- epilogue: nonlin b1 @ T-1 (LDS only), fc for both final steps ----
    if (tid >= 256 && tid < 512) {
        const int rr = tid - 256;
        const float gi = gbuf1[rr];
        const float gf = gate1;
        const float gg = gbuf1[256 + rr];
        const float go = gbuf1[512 + rr];
        const float i_ = 1.f / (1.f + __expf(-gi));
        const float f_ = 1.f / (1.f + __expf(-gf));
        const float g_ = 2.f / (1.f + __expf(-2.f * gg)) - 1.f;
        const float oo = 1.f / (1.f + __expf(-go));
        c_state = f_ * c_state + i_ * g_;
        const float tc = 2.f / (1.f + __expf(-2.f * c_state)) - 1.f;
        ((_Float16*)hf16b)[rr] = (_Float16)(oo * tc);
    }
    fc_step(hf16a, out0, T_ - 1, fw, fcb_v, o_, kc);
    __syncthreads();
    fc_step(hf16b, out1, T_ - 1, fw, fcb_v, o_, kc);
}

extern "C" void kernel_launch(void* const* d_in, const int* in_sizes, int n_in,
                              void* d_out, int out_size, void* d_ws, size_t ws_size,
                              hipStream_t stream) {
    const float* x    = (const float*)d_in[0];
    const float* Wih  = (const float*)d_in[1];
    const float* Whh  = (const float*)d_in[2];
    const float* bih  = (const float*)d_in[3];
    const float* bhh  = (const float*)d_in[4];
    const float* fcw  = (const float*)d_in[5];
    const float* fcb  = (const float*)d_in[6];
    float* out = (float*)d_out;

    char* ws = (char*)d_ws;
    uint32_t* qwhh = (uint32_t*)(ws + QWHH_OFF);
    uint32_t* qwih = (uint32_t*)(ws + QWIH_OFF);
    float*    s1   = (float*)(ws + S1_OFF);
    float*    s2   = (float*)(ws + S2_OFF);
    float*    bias = (float*)(ws + BIAS_OFF);
    uint32_t* xq   = (uint32_t*)(ws + XQ_OFF);
    float*    xs   = (float*)(ws + XS_OFF);
    char*     hbuf = ws + HBUF_OFF;

    prep_w<<<G4, 64, 0, stream>>>(Whh, Wih, bih, bhh, qwhh, qwih, s1, s2, bias);
    prep_x<<<(B_ * T_) / 64, 256, 0, stream>>>(x, xq, xs);
    lstm_main<<<B_ / 2, 1024, 0, stream>>>(qwhh, qwih, s1, s2, bias, xq, xs,
                                           fcw, fcb, hbuf, out);
}

// Round 3
// 5395.201 us; speedup vs baseline: 1.2103x; 1.2103x over previous
//
#include <hip/hip_runtime.h>
#include <cstdint>

// LSTM fused kernel for MI355X — round 5: single-barrier step.
// 64 blocks x 1024 threads. New gate-row mapping: wave w, lane l computes
// gate G=l/16 of row w*16+(l&15), so all 4 gates of a row live in ONE wave
// -> gate exchange is 3 shfl_xor + 8 cndmask (no LDS, no barrier A).
// Per-16-row quant scales (16 f32, record stays 320 B) make the quant max a
// wave-local DPP reduce. One barrier per step: h s_loads + fc(t-1) share one
// lgkm drain window; x_contrib(t+1) s_load miss overlaps the h-store ack
// drain before the barrier. hf16 double-buffered (read t-1 / write t race).

#define B_  64
#define T_  2048
#define I_  32
#define H_  256
#define G4  1024
#define O_  32

typedef int v16i __attribute__((ext_vector_type(16)));
typedef unsigned int v4u __attribute__((ext_vector_type(4)));
typedef _Float16 h2_t __attribute__((ext_vector_type(2)));

#if __has_builtin(__builtin_amdgcn_sdot4)
__device__ __forceinline__ int dot4(int a, int b, int c) {
    return __builtin_amdgcn_sdot4(a, b, c, false);
}
#else
__device__ __forceinline__ int dot4(int a, int b, int c) {
    c += (int)(int8_t)(a)        * (int)(int8_t)(b);
    c += (int)(int8_t)(a >> 8)   * (int)(int8_t)(b >> 8);
    c += (int)(int8_t)(a >> 16)  * (int)(int8_t)(b >> 16);
    c += (int)(int8_t)(a >> 24)  * (int)(int8_t)(b >> 24);
    return c;
}
#endif

__device__ __forceinline__ float fdot2h(h2_t a, h2_t b, float c) {
#if __has_builtin(__builtin_amdgcn_fdot2)
    return __builtin_amdgcn_fdot2(a, b, c, false);
#else
    return c + (float)a[0] * (float)b[0] + (float)a[1] * (float)b[1];
#endif
}

// ---- DPP cross-lane reductions (VALU pipe; keep lgkm clean) ----
__device__ __forceinline__ float wave64_max_bcast(float v) {
    int t;
    t = __builtin_amdgcn_update_dpp(__float_as_int(v), __float_as_int(v), 0x111, 0xf, 0xf, false);
    v = fmaxf(v, __int_as_float(t));
    t = __builtin_amdgcn_update_dpp(__float_as_int(v), __float_as_int(v), 0x112, 0xf, 0xf, false);
    v = fmaxf(v, __int_as_float(t));
    t = __builtin_amdgcn_update_dpp(__float_as_int(v), __float_as_int(v), 0x114, 0xf, 0xf, false);
    v = fmaxf(v, __int_as_float(t));
    t = __builtin_amdgcn_update_dpp(__float_as_int(v), __float_as_int(v), 0x118, 0xf, 0xf, false);
    v = fmaxf(v, __int_as_float(t));
    t = __builtin_amdgcn_update_dpp(__float_as_int(v), __float_as_int(v), 0x142, 0xa, 0xf, false);
    v = fmaxf(v, __int_as_float(t));
    t = __builtin_amdgcn_update_dpp(__float_as_int(v), __float_as_int(v), 0x143, 0xc, 0xf, false);
    v = fmaxf(v, __int_as_float(t));
    return __int_as_float(__builtin_amdgcn_readlane(__float_as_int(v), 63));
}

// sum within each 32-lane half; lane31 holds sum(0..31), lane63 sum(32..63).
__device__ __forceinline__ float halfwave_sum31(float v) {
    int t;
    t = __builtin_amdgcn_update_dpp(0, __float_as_int(v), 0x111, 0xf, 0xf, true); v += __int_as_float(t);
    t = __builtin_amdgcn_update_dpp(0, __float_as_int(v), 0x112, 0xf, 0xf, true); v += __int_as_float(t);
    t = __builtin_amdgcn_update_dpp(0, __float_as_int(v), 0x114, 0xf, 0xf, true); v += __int_as_float(t);
    t = __builtin_amdgcn_update_dpp(0, __float_as_int(v), 0x118, 0xf, 0xf, true); v += __int_as_float(t);
    t = __builtin_amdgcn_update_dpp(0, __float_as_int(v), 0x142, 0xa, 0xf, true); v += __int_as_float(t);
    return v;
}

// ---------------- ws layout (all 256-B aligned) ----------------
#define QWHH_OFF 0
#define QWIH_OFF 262144
#define S1_OFF   327680
#define S2_OFF   331776
#define BIAS_OFF 335872
#define XQ_OFF   339968
#define XS_OFF   8728576
#define HBUF_OFF 9252864
#define HREC_STRIDE 320
#define HSLOTS 2049

__device__ __forceinline__ uint32_t pack_q(int q0, int q1, int q2, int q3) {
    return  ((uint32_t)(uint8_t)(int8_t)q0)
          | (((uint32_t)(uint8_t)(int8_t)q1) << 8)
          | (((uint32_t)(uint8_t)(int8_t)q2) << 16)
          | (((uint32_t)(uint8_t)(int8_t)q3) << 24);
}

__device__ __forceinline__ int clamp127(int v) {
    return v < -127 ? -127 : (v > 127 ? 127 : v);
}

// -------- prep: quantize weights (1 block of 64 thr per gate-row) --------
__global__ __launch_bounds__(64) void prep_w(
    const float* __restrict__ Whh, const float* __restrict__ Wih,
    const float* __restrict__ bih, const float* __restrict__ bhh,
    uint32_t* __restrict__ qwhh, uint32_t* __restrict__ qwih,
    float* __restrict__ s1, float* __restrict__ s2, float* __restrict__ bias)
{
    const int r = blockIdx.x;
    const int l = threadIdx.x;

    const float4 wv = ((const float4*)(Whh + r * H_))[l];
    float m = fmaxf(fmaxf(fabsf(wv.x), fabsf(wv.y)), fmaxf(fabsf(wv.z), fabsf(wv.w)));
    #pragma unroll
    for (int s = 1; s < 64; s <<= 1) m = fmaxf(m, __shfl_xor(m, s, 64));
    const float S1 = fmaxf(m, 1e-20f) / 127.f;

    float xm = (l < I_) ? fabsf(Wih[r * I_ + l]) : 0.f;
    #pragma unroll
    for (int s = 1; s < 64; s <<= 1) xm = fmaxf(xm, __shfl_xor(xm, s, 64));
    const float S2 = fmaxf(xm, 1e-20f) / 127.f;

    {
        const float r1 = 1.f / S1;
        qwhh[l * G4 + r] = pack_q(
            clamp127((int)rintf(wv.x * r1)), clamp127((int)rintf(wv.y * r1)),
            clamp127((int)rintf(wv.z * r1)), clamp127((int)rintf(wv.w * r1)));
    }
    if (l < 8) {
        const float4 xw = ((const float4*)(Wih + r * I_))[l];
        const float r2 = 1.f / S2;
        qwih[l * G4 + r] = pack_q(
            clamp127((int)rintf(xw.x * r2)), clamp127((int)rintf(xw.y * r2)),
            clamp127((int)rintf(xw.z * r2)), clamp127((int)rintf(xw.w * r2)));
    } else if (l < 16) {
        const int j = l - 8;
        const float4 xw = ((const float4*)(Wih + r * I_))[j];
        const float r2 = 1.f / S2;
        float v0 = xw.x * r2, v1 = xw.y * r2, v2 = xw.z * r2, v3 = xw.w * r2;
        int a0 = clamp127((int)rintf(v0)), a1 = clamp127((int)rintf(v1));
        int a2 = clamp127((int)rintf(v2)), a3 = clamp127((int)rintf(v3));
        qwih[(8 + j) * G4 + r] = pack_q(
            clamp127((int)rintf((v0 - (float)a0) * 127.f)),
            clamp127((int)rintf((v1 - (float)a1) * 127.f)),
            clamp127((int)rintf((v2 - (float)a2) * 127.f)),
            clamp127((int)rintf((v3 - (float)a3) * 127.f)));
    }
    if (l == 0) { s1[r] = S1; s2[r] = S2; bias[r] = bih[r] + bhh[r]; }
}

// -------- prep: quantize x (64 (b,t) rows per block) --------
__global__ __launch_bounds__(256) void prep_x(
    const float* __restrict__ x, uint32_t* __restrict__ xq, float* __restrict__ xs)
{
    __shared__ float xb[64 * 32];
    const int base = blockIdx.x * 64 * 32;
    for (int i = threadIdx.x; i < 2048; i += 256) xb[i] = x[base + i];
    __syncthreads();
    const int t = threadIdx.x;
    if (t < 64) {
        float m = 0.f;
        for (int k = 0; k < 32; k++) m = fmaxf(m, fabsf(xb[t * 32 + k]));
        const float S = fmaxf(m, 1e-20f) / 127.f;
        const int row = blockIdx.x * 64 + t;
        xs[row] = S;
        const float rS = 1.f / S;
        for (int j = 0; j < 8; j++) {
            int qa[4], qb[4];
            for (int e = 0; e < 4; e++) {
                float v = xb[t * 32 + j * 4 + e] * rS;
                int a = clamp127((int)rintf(v));
                int b = clamp127((int)rintf((v - (float)a) * 127.f));
                qa[e] = a; qb[e] = b;
            }
            xq[row * 16 + j]     = pack_q(qa[0], qa[1], qa[2], qa[3]);
            xq[row * 16 + 8 + j] = pack_q(qb[0], qb[1], qb[2], qb[3]);
        }
    }
}

// x contribution for one (b,t): scalar loads + int8 dots (hi/lo split)
__device__ __forceinline__ float x_contrib(const uint32_t* pxq, const float* pxs,
                                           const uint32_t* wA, const uint32_t* wB,
                                           float S2, float bias_r) {
    v16i xv; int sxi;
    asm volatile("s_load_dwordx16 %0, %2, 0x0\n\t"
                 "s_load_dword %1, %3, 0x0\n\t"
                 "s_waitcnt lgkmcnt(0)"
                 : "=&s"(xv), "=&s"(sxi)
                 : "s"(pxq), "s"(pxs)
                 : "memory");
    int aA = 0, aM = 0;
    #pragma unroll
    for (int j = 0; j < 8; j++) {
        aA = dot4((int)wA[j], xv[j],     aA);
        aM = dot4((int)wA[j], xv[8 + j], aM);
        aM = dot4((int)wB[j], xv[j],     aM);
    }
    return ((float)aA + (float)aM * (1.f / 127.f)) * (S2 * __int_as_float(sxi)) + bias_r;
}

// fc for one timestep from an LDS f16 h-buffer (DPP reduce; lanes 31/63 store)
__device__ __forceinline__ void fc_step(const uint32_t* hfbuf, float* outp, int trow,
                                        const h2_t* fw, float fcb_v, int o_, int kc) {
    const v4u hv = *(const v4u*)(&hfbuf[4 * kc]);
    union { uint32_t u; h2_t h; } u0, u1, u2, u3;
    u0.u = hv[0]; u1.u = hv[1]; u2.u = hv[2]; u3.u = hv[3];
    float acc = 0.f;
    acc = fdot2h(fw[0], u0.h, acc);
    acc = fdot2h(fw[1], u1.h, acc);
    acc = fdot2h(fw[2], u2.h, acc);
    acc = fdot2h(fw[3], u3.h, acc);
    acc = halfwave_sum31(acc);
    if (kc == 31) outp[trow * O_ + o_] = acc + fcb_v;
}

// -------- main: full LSTM + fc, one block per batch, single-barrier step --------
__global__ __launch_bounds__(1024, 4) void lstm_main(
    const uint32_t* __restrict__ qwhh, const uint32_t* __restrict__ qwih,
    const float* __restrict__ s1v, const float* __restrict__ s2v,
    const float* __restrict__ biasv,
    const uint32_t* __restrict__ xq, const float* __restrict__ xs,
    const float* __restrict__ fcw, const float* __restrict__ fcb,
    char* __restrict__ hbuf, float* __restrict__ out)
{
    const int b   = blockIdx.x;
    const int tid = threadIdx.x;
    const int wv  = tid >> 6;        // wave 0..15
    const int ln  = tid & 63;        // lane
    const int G   = ln >> 4;         // gate 0..3 (i,f,g,o)
    const int r16 = ln & 15;         // row within wave
    const int grow = G * 256 + wv * 16 + r16;   // gate-row 0..1023

    __shared__ uint32_t hf16[2][128];  // double-buffered h f16 (for fc)

    // resident int8 weights for gate-row `grow`
    uint32_t w[64], wA[8], wB[8];
    #pragma unroll
    for (int d = 0; d < 64; d++) w[d] = qwhh[d * G4 + grow];
    #pragma unroll
    for (int j = 0; j < 8; j++) { wA[j] = qwih[j * G4 + grow]; wB[j] = qwih[(8 + j) * G4 + grow]; }
    const float S1 = s1v[grow], S2 = s2v[grow], bias_r = biasv[grow];

    // fc weights f16 in regs (tid-based mapping, independent of grow)
    const int o_ = tid >> 5, kc = tid & 31;
    h2_t fw[4];
    {
        const float* fr = fcw + o_ * H_ + kc * 8;
        #pragma unroll
        for (int j = 0; j < 4; j++) {
            h2_t p; p[0] = (_Float16)fr[2 * j]; p[1] = (_Float16)fr[2 * j + 1];
            fw[j] = p;
        }
    }
    const float fcb_v = fcb[o_];

    char* hb = hbuf + (size_t)b * (HSLOTS * HREC_STRIDE);
    {   // init zero record (slot 2048): 256 B h + 64 B scales
        char* z = hb + 2048 * HREC_STRIDE;
        if (tid < 256)      z[tid] = 0;
        else if (tid < 272) ((uint32_t*)(z + 256))[tid - 256] = 0;
    }

    const uint32_t* xqb  = xq + (size_t)(b * T_) * 16;
    const float*    xsb  = xs + (size_t)(b * T_);
    float*          outb = out + (size_t)(b * T_) * O_;

    float c_state = 0.f;   // replicated x4 per row (identical arithmetic)
    float xp = x_contrib(xqb, xsb, wA, wB, S2, bias_r);   // t = 0

    __syncthreads();  // drain zero-record stores

    for (int t = 0; t < T_; t++) {
        // --- issue h-record scalar loads (256 int8 + 16 f32 scales), no wait ---
        const uint32_t slot = (t == 0) ? 2048u : ((uint32_t)(t * 1993) & 2047u);
        const char* hrec = hb + (size_t)slot * HREC_STRIDE;
        v16i h0, h1, h2, h3, scv;
        asm volatile("s_load_dwordx16 %0, %5, 0x0\n\t"
                     "s_load_dwordx16 %1, %5, 0x40\n\t"
                     "s_load_dwordx16 %2, %5, 0x80\n\t"
                     "s_load_dwordx16 %3, %5, 0xc0\n\t"
                     "s_load_dwordx16 %4, %5, 0x100"
                     : "=&s"(h0), "=&s"(h1), "=&s"(h2), "=&s"(h3), "=&s"(scv)
                     : "s"(hrec)
                     : "memory");

        // --- fc(t-1): its ds_read forces lgkmcnt(0) == the h-load drain ---
        if (t > 0)
            fc_step(&hf16[(t - 1) & 1][0], outb, t - 1, fw, fcb_v, o_, kc);

        asm volatile("s_waitcnt lgkmcnt(0)"
                     : "+s"(h0), "+s"(h1), "+s"(h2), "+s"(h3), "+s"(scv)
                     :
                     : "memory");

        // --- GEMV: 16 scale groups of 16 columns each ---
        float hs0 = 0.f, hs1 = 0.f, hs2 = 0.f, hs3 = 0.f;
        #pragma unroll
        for (int g = 0; g < 4; g++) {
            int a = 0;
            #pragma unroll
            for (int j = 0; j < 4; j++) a = dot4((int)w[4 * g + j], h0[4 * g + j], a);
            hs0 = fmaf((float)a, __int_as_float(scv[g]), hs0);
        }
        #pragma unroll
        for (int g = 0; g < 4; g++) {
            int a = 0;
            #pragma unroll
            for (int j = 0; j < 4; j++) a = dot4((int)w[16 + 4 * g + j], h1[4 * g + j], a);
            hs1 = fmaf((float)a, __int_as_float(scv[4 + g]), hs1);
        }
        #pragma unroll
        for (int g = 0; g < 4; g++) {
            int a = 0;
            #pragma unroll
            for (int j = 0; j < 4; j++) a = dot4((int)w[32 + 4 * g + j], h2[4 * g + j], a);
            hs2 = fmaf((float)a, __int_as_float(scv[8 + g]), hs2);
        }
        #pragma unroll
        for (int g = 0; g < 4; g++) {
            int a = 0;
            #pragma unroll
            for (int j = 0; j < 4; j++) a = dot4((int)w[48 + 4 * g + j], h3[4 * g + j], a);
            hs3 = fmaf((float)a, __int_as_float(scv[12 + g]), hs3);
        }
        const float gate = ((hs0 + hs1) + (hs2 + hs3)) * S1 + xp;

        // --- intra-wave gate exchange: row r's 4 gates live at lanes l^{0,16,32,48} ---
        const float vB = __shfl_xor(gate, 16, 64);
        const float vC = __shfl_xor(gate, 32, 64);
        const float vD = __shfl_xor(gate, 48, 64);
        const bool s0 = (G & 1), s1b = (G & 2);
        const float p00 = s0 ? vB : gate, p01 = s0 ? gate : vB;
        const float p10 = s0 ? vD : vC,   p11 = s0 ? vC : vD;
        const float gi = s1b ? p10 : p00;
        const float gf = s1b ? p11 : p01;
        const float gg = s1b ? p00 : p10;
        const float go = s1b ? p01 : p11;

        // --- nonlinearity (all lanes; replicas stay bit-identical) ---
        const float i_ = 1.f / (1.f + __expf(-gi));
        const float f_ = 1.f / (1.f + __expf(-gf));
        const float g_ = 2.f / (1.f + __expf(-2.f * gg)) - 1.f;
        const float oo = 1.f / (1.f + __expf(-go));
        c_state = f_ * c_state + i_ * g_;
        const float tc = 2.f / (1.f + __expf(-2.f * c_state)) - 1.f;
        const float hval = oo * tc;

        // --- quant (per-16-row group = this wave) + publish ---
        const uint32_t wslot = (uint32_t)((t + 1) * 1993) & 2047u;
        char* hw = hb + (size_t)wslot * HREC_STRIDE;
        float m = wave64_max_bcast(fabsf(hval));
        m = fmaxf(m, 1e-12f);
        const float rq = 127.f / m;
        const int q = clamp127((int)rintf(hval * rq));
        if (G == 0) {
            hw[wv * 16 + r16] = (char)(int8_t)q;
            ((_Float16*)&hf16[t & 1][0])[wv * 16 + r16] = (_Float16)hval;
        }
        if (ln == 0)
            ((float*)(hw + 256))[wv] = m * (1.f / 127.f);

        // --- x contribution for t+1: load miss overlaps h-store ack drain ---
        const int tn = (t + 1 < T_) ? (t + 1) : t;
        xp = x_contrib(xqb + (size_t)tn * 16, xsb + tn, wA, wB, S2, bias_r);

        __syncthreads();   // single barrier: publishes h record + hf16[t&1]
    }

    // epilogue: fc for the final timestep
    fc_step(&hf16[(T_ - 1) & 1][0], outb, T_ - 1, fw, fcb_v, o_, kc);
}

extern "C" void kernel_launch(void* const* d_in, const int* in_sizes, int n_in,
                              void* d_out, int out_size, void* d_ws, size_t ws_size,
                              hipStream_t stream) {
    const float* x    = (const float*)d_in[0];
    const float* Wih  = (const float*)d_in[1];
    const float* Whh  = (const float*)d_in[2];
    const float* bih  = (const float*)d_in[3];
    const float* bhh  = (const float*)d_in[4];
    const float* fcw  = (const float*)d_in[5];
    const float* fcb  = (const float*)d_in[6];
    float* out = (float*)d_out;

    char* ws = (char*)d_ws;
    uint32_t* qwhh = (uint32_t*)(ws + QWHH_OFF);
    uint32_t* qwih = (uint32_t*)(ws + QWIH_OFF);
    float*    s1   = (float*)(ws + S1_OFF);
    float*    s2   = (float*)(ws + S2_OFF);
    float*    bias = (float*)(ws + BIAS_OFF);
    uint32_t* xq   = (uint32_t*)(ws + XQ_OFF);
    float*    xs   = (float*)(ws + XS_OFF);
    char*     hbuf = ws + HBUF_OFF;

    prep_w<<<G4, 64, 0, stream>>>(Whh, Wih, bih, bhh, qwhh, qwih, s1, s2, bias);
    prep_x<<<(B_ * T_) / 64, 256, 0, stream>>>(x, xq, xs);
    lstm_main<<<B_, 1024, 0, stream>>>(qwhh, qwih, s1, s2, bias, xq, xs,
                                       fcw, fcb, hbuf, out);
}

// Round 4
// 3410.482 us; speedup vs baseline: 1.9146x; 1.5819x over previous
//
#include <hip/hip_runtime.h>
#include <cstdint>

// LSTM fused kernel for MI355X — round 6: 4-wave in-lane step, LDS h-ring.
// 64 blocks x 256 threads (1 wave/SIMD). Thread r owns ALL FOUR gate rows of
// h-row r -> no gate exchange, no redundant nonlin, one barrier per step.
// h stays in LDS (int8 + 4 group scales, double-buffered 272B record) read as
// broadcast ds_read_b128 -> the 800-1000cy global h round-trip of round 2
// becomes ~150cy. Raw s_barrier + lgkmcnt(0) only (no vmcnt drain: fc output
// stores float freely). x contribution via f16 fdot2 (x pre-cast to f16,
// W_ih f16 in VGPRs) — more accurate than the old int8 x path.

#define B_  64
#define T_  2048
#define I_  32
#define H_  256
#define O_  32

typedef unsigned int v4u __attribute__((ext_vector_type(4)));
typedef _Float16 h2_t __attribute__((ext_vector_type(2)));

#if __has_builtin(__builtin_amdgcn_sdot4)
__device__ __forceinline__ int dot4(int a, int b, int c) {
    return __builtin_amdgcn_sdot4(a, b, c, false);
}
#else
__device__ __forceinline__ int dot4(int a, int b, int c) {
    c += (int)(int8_t)(a)        * (int)(int8_t)(b);
    c += (int)(int8_t)(a >> 8)   * (int)(int8_t)(b >> 8);
    c += (int)(int8_t)(a >> 16)  * (int)(int8_t)(b >> 16);
    c += (int)(int8_t)(a >> 24)  * (int)(int8_t)(b >> 24);
    return c;
}
#endif

__device__ __forceinline__ float fdot2h(h2_t a, h2_t b, float c) {
#if __has_builtin(__builtin_amdgcn_fdot2)
    return __builtin_amdgcn_fdot2(a, b, c, false);
#else
    return c + (float)a[0] * (float)b[0] + (float)a[1] * (float)b[1];
#endif
}

// ---- DPP reductions (VALU pipe) ----
__device__ __forceinline__ float wave64_max_bcast(float v) {
    int t;
    t = __builtin_amdgcn_update_dpp(__float_as_int(v), __float_as_int(v), 0x111, 0xf, 0xf, false);
    v = fmaxf(v, __int_as_float(t));
    t = __builtin_amdgcn_update_dpp(__float_as_int(v), __float_as_int(v), 0x112, 0xf, 0xf, false);
    v = fmaxf(v, __int_as_float(t));
    t = __builtin_amdgcn_update_dpp(__float_as_int(v), __float_as_int(v), 0x114, 0xf, 0xf, false);
    v = fmaxf(v, __int_as_float(t));
    t = __builtin_amdgcn_update_dpp(__float_as_int(v), __float_as_int(v), 0x118, 0xf, 0xf, false);
    v = fmaxf(v, __int_as_float(t));
    t = __builtin_amdgcn_update_dpp(__float_as_int(v), __float_as_int(v), 0x142, 0xa, 0xf, false);
    v = fmaxf(v, __int_as_float(t));
    t = __builtin_amdgcn_update_dpp(__float_as_int(v), __float_as_int(v), 0x143, 0xc, 0xf, false);
    v = fmaxf(v, __int_as_float(t));
    return __int_as_float(__builtin_amdgcn_readlane(__float_as_int(v), 63));
}

// sum over each group of 8 consecutive lanes; lane (8k+7) holds its group sum.
__device__ __forceinline__ float sum8(float v) {
    int t;
    t = __builtin_amdgcn_update_dpp(0, __float_as_int(v), 0x111, 0xf, 0xf, true); v += __int_as_float(t);
    t = __builtin_amdgcn_update_dpp(0, __float_as_int(v), 0x112, 0xf, 0xf, true); v += __int_as_float(t);
    t = __builtin_amdgcn_update_dpp(0, __float_as_int(v), 0x114, 0xf, 0xf, true); v += __int_as_float(t);
    return v;
}

// ---------------- ws layout (256-B aligned) ----------------
// qw4  : u32 [64 v4u-groups][256 r][4]   (0)       262144 B
// wih4 : u32 [16][256][4] (f16x2)        (262144)  65536 B
// s1v  : f32 [1024]                      (327680)  4096 B
// biasv: f32 [1024]                      (331776)  4096 B
// xh   : f16 [B*T*32]                    (335872)  8388608 B
#define QW_OFF   0
#define WIH_OFF  262144
#define S1_OFF   327680
#define BIAS_OFF 331776
#define XH_OFF   335872

__device__ __forceinline__ uint32_t pack_q(int q0, int q1, int q2, int q3) {
    return  ((uint32_t)(uint8_t)(int8_t)q0)
          | (((uint32_t)(uint8_t)(int8_t)q1) << 8)
          | (((uint32_t)(uint8_t)(int8_t)q2) << 16)
          | (((uint32_t)(uint8_t)(int8_t)q3) << 24);
}

__device__ __forceinline__ int clamp127(int v) {
    return v < -127 ? -127 : (v > 127 ? 127 : v);
}

// -------- prep: quantize Whh (int8, per-row scale), Wih -> f16, bias --------
// grid = 1024 blocks (one per gate-row), 64 threads (one per 4-col chunk)
__global__ __launch_bounds__(64) void prep_w(
    const float* __restrict__ Whh, const float* __restrict__ Wih,
    const float* __restrict__ bih, const float* __restrict__ bhh,
    uint32_t* __restrict__ qw4, uint32_t* __restrict__ wih4,
    float* __restrict__ s1v, float* __restrict__ biasv)
{
    const int gr = blockIdx.x;          // gate-row 0..1023
    const int c  = threadIdx.x;         // float4 chunk 0..63
    const int j  = gr >> 8;             // gate 0..3
    const int r  = gr & 255;            // h-row

    const float4 wv = ((const float4*)(Whh + gr * H_))[c];
    float m = fmaxf(fmaxf(fabsf(wv.x), fabsf(wv.y)), fmaxf(fabsf(wv.z), fabsf(wv.w)));
    #pragma unroll
    for (int s = 1; s < 64; s <<= 1) m = fmaxf(m, __shfl_xor(m, s, 64));
    const float S1 = fmaxf(m, 1e-20f) / 127.f;
    const float r1 = 1.f / S1;

    {   // Whh int8, layout: thread r loads v4u at [d4*256 + r]
        const int d = j * 64 + c;       // dword index 0..255 for row r
        qw4[(d >> 2) * 1024 + r * 4 + (d & 3)] = pack_q(
            clamp127((int)rintf(wv.x * r1)), clamp127((int)rintf(wv.y * r1)),
            clamp127((int)rintf(wv.z * r1)), clamp127((int)rintf(wv.w * r1)));
    }
    if (c < 16) {  // Wih as f16 pairs: dword dd covers cols 2c, 2c+1
        union { uint32_t u; h2_t h; } z;
        z.h[0] = (_Float16)Wih[gr * I_ + 2 * c];
        z.h[1] = (_Float16)Wih[gr * I_ + 2 * c + 1];
        const int dd = j * 16 + c;
        wih4[(dd >> 2) * 1024 + r * 4 + (dd & 3)] = z.u;
    }
    if (c == 0) { s1v[gr] = S1; biasv[gr] = bih[gr] + bhh[gr]; }
}

// -------- prep: cast x f32 -> f16 pairs --------
__global__ __launch_bounds__(256) void prep_xh(
    const float* __restrict__ x, uint32_t* __restrict__ xh)
{
    const int i = blockIdx.x * 256 + threadIdx.x;   // dword index < B*T*16
    const float2 v = ((const float2*)x)[i];
    union { uint32_t u; h2_t h; } z;
    z.h[0] = (_Float16)v.x; z.h[1] = (_Float16)v.y;
    xh[i] = z.u;
}

// -------- main: 64 blocks x 256 threads, in-lane step, LDS h-ring --------
__global__ __launch_bounds__(256, 1) void lstm_main(
    const uint32_t* __restrict__ qw4, const uint32_t* __restrict__ wih4,
    const float* __restrict__ s1v, const float* __restrict__ biasv,
    const uint32_t* __restrict__ xh, const float* __restrict__ fcw,
    const float* __restrict__ fcb, float* __restrict__ out)
{
    const int b  = blockIdx.x;
    const int r  = threadIdx.x;       // h-row 0..255
    const int ln = r & 63;
    const int wv = r >> 6;            // quant scale group (64 rows)

    __shared__ uint32_t hqb[2][64];                   // h int8, double-buffered
    __shared__ __align__(16) float hscb[2][4];        // 4 group scales
    __shared__ uint32_t hfb[2][128];                  // h f16 (for fc)

    // ---- resident weights ----
    v4u w4[64];                                       // Whh rows {r,256+r,512+r,768+r}
    #pragma unroll
    for (int d4 = 0; d4 < 64; d4++) w4[d4] = ((const v4u*)qw4)[d4 * 256 + r];
    v4u wx[16];                                       // Wih f16 pairs
    #pragma unroll
    for (int d4 = 0; d4 < 16; d4++) wx[d4] = ((const v4u*)wih4)[d4 * 256 + r];
    float S1j[4], bj[4];
    #pragma unroll
    for (int j = 0; j < 4; j++) { S1j[j] = s1v[j * 256 + r]; bj[j] = biasv[j * 256 + r]; }

    // fc weights f16: o_=r>>3 (0..31), ks=r&7 -> k in [32ks, 32ks+32)
    const int o_ = r >> 3, ks = r & 7;
    h2_t fw[16];
    {
        const float* fr = fcw + o_ * H_ + ks * 32;
        #pragma unroll
        for (int i = 0; i < 16; i++) {
            h2_t p; p[0] = (_Float16)fr[2 * i]; p[1] = (_Float16)fr[2 * i + 1];
            fw[i] = p;
        }
    }
    const float fcb_v = fcb[o_];

    if (r < 4) hscb[1][r] = 0.f;      // t=0 reads buffer 1: zero scales => h-sum 0
    __syncthreads();

    const uint32_t* xb   = xh + (size_t)(b * T_) * 16;
    float*          outb = out + (size_t)(b * T_) * O_;

    float c_state = 0.f;

    for (int t = 0; t < T_; t++) {
        const int pb = (t & 1) ^ 1, cb = t & 1;

        // x for this step (wave-uniform loads; covered by the dot phase)
        const v4u* xv = (const v4u*)(xb + (size_t)t * 16);
        const v4u x0 = xv[0], x1 = xv[1], x2 = xv[2], x3 = xv[3];

        // h broadcast (LDS, same-address = conflict-free) + scales
        const v4u*   hqv = (const v4u*)&hqb[pb][0];
        const float4 scv = *(const float4*)&hscb[pb][0];
        const float  scar[4] = { scv.x, scv.y, scv.z, scv.w };

        // ---- h GEMV: 4 gate rows x 256 cols, 4 scale groups ----
        float a0 = 0.f, a1 = 0.f, a2 = 0.f, a3 = 0.f;
        #pragma unroll
        for (int g = 0; g < 4; g++) {
            v4u hg[4];
            #pragma unroll
            for (int q = 0; q < 4; q++) hg[q] = hqv[g * 4 + q];
            int i0 = 0, i1 = 0, i2 = 0, i3 = 0;
            #pragma unroll
            for (int q = 0; q < 4; q++) {
                #pragma unroll
                for (int e = 0; e < 4; e++) {
                    const int hv = (int)hg[q][e];
                    i0 = dot4((int)w4[ 0 + g * 4 + q][e], hv, i0);
                    i1 = dot4((int)w4[16 + g * 4 + q][e], hv, i1);
                    i2 = dot4((int)w4[32 + g * 4 + q][e], hv, i2);
                    i3 = dot4((int)w4[48 + g * 4 + q][e], hv, i3);
                }
            }
            a0 = fmaf((float)i0, scar[g], a0);
            a1 = fmaf((float)i1, scar[g], a1);
            a2 = fmaf((float)i2, scar[g], a2);
            a3 = fmaf((float)i3, scar[g], a3);
        }

        // ---- fc(t-1) pipelined (independent of this step's h) ----
        if (t > 0) {
            const v4u* hfv = (const v4u*)&hfb[pb][0];
            v4u fh[4];
            #pragma unroll
            for (int i = 0; i < 4; i++) fh[i] = hfv[ks * 4 + i];
            float acc = 0.f;
            #pragma unroll
            for (int i = 0; i < 16; i++) {
                union { uint32_t u; h2_t h; } z;
                z.u = fh[i >> 2][i & 3];
                acc = fdot2h(fw[i], z.h, acc);
            }
            acc = sum8(acc);
            if (ks == 7) outb[(t - 1) * O_ + o_] = acc + fcb_v;
        }

        // ---- x contribution (f16 dots) ----
        float xd0 = 0.f, xd1 = 0.f, xd2 = 0.f, xd3 = 0.f;
        {
            const v4u xg4[4] = { x0, x1, x2, x3 };
            #pragma unroll
            for (int d4 = 0; d4 < 4; d4++) {
                #pragma unroll
                for (int e = 0; e < 4; e++) {
                    union { uint32_t u; h2_t h; } zx, z0, z1, z2, z3;
                    zx.u = xg4[d4][e];
                    z0.u = wx[ 0 + d4][e]; xd0 = fdot2h(z0.h, zx.h, xd0);
                    z1.u = wx[ 4 + d4][e]; xd1 = fdot2h(z1.h, zx.h, xd1);
                    z2.u = wx[ 8 + d4][e]; xd2 = fdot2h(z2.h, zx.h, xd2);
                    z3.u = wx[12 + d4][e]; xd3 = fdot2h(z3.h, zx.h, xd3);
                }
            }
        }

        // ---- gates + nonlinearity (all in-lane, once per row) ----
        const float g0 = fmaf(a0, S1j[0], xd0 + bj[0]);
        const float g1 = fmaf(a1, S1j[1], xd1 + bj[1]);
        const float g2 = fmaf(a2, S1j[2], xd2 + bj[2]);
        const float g3 = fmaf(a3, S1j[3], xd3 + bj[3]);
        const float i_ = 1.f / (1.f + __expf(-g0));
        const float f_ = 1.f / (1.f + __expf(-g1));
        const float gg = 2.f / (1.f + __expf(-2.f * g2)) - 1.f;
        const float oo = 1.f / (1.f + __expf(-g3));
        c_state = f_ * c_state + i_ * gg;
        const float tc = 2.f / (1.f + __expf(-2.f * c_state)) - 1.f;
        const float hval = oo * tc;

        // ---- quantize + publish to LDS (double-buffered) ----
        float m = wave64_max_bcast(fabsf(hval));
        m = fmaxf(m, 1e-12f);
        const int q = clamp127((int)rintf(hval * (127.f / m)));
        ((char*)&hqb[cb][0])[r] = (char)(int8_t)q;
        if (ln == 0) hscb[cb][wv] = m * (1.f / 127.f);
        ((_Float16*)&hfb[cb][0])[r] = (_Float16)hval;

        // one barrier per step; LDS-only drain (no vmcnt: stores fly free)
        asm volatile("s_waitcnt lgkmcnt(0)" ::: "memory");
        __builtin_amdgcn_s_barrier();
    }

    // ---- epilogue: fc for t = T-1 ----
    {
        const int pb = (T_ - 1) & 1;
        const v4u* hfv = (const v4u*)&hfb[pb][0];
        v4u fh[4];
        #pragma unroll
        for (int i = 0; i < 4; i++) fh[i] = hfv[ks * 4 + i];
        float acc = 0.f;
        #pragma unroll
        for (int i = 0; i < 16; i++) {
            union { uint32_t u; h2_t h; } z;
            z.u = fh[i >> 2][i & 3];
            acc = fdot2h(fw[i], z.h, acc);
        }
        acc = sum8(acc);
        if (ks == 7) outb[(T_ - 1) * O_ + o_] = acc + fcb_v;
    }
}

extern "C" void kernel_launch(void* const* d_in, const int* in_sizes, int n_in,
                              void* d_out, int out_size, void* d_ws, size_t ws_size,
                              hipStream_t stream) {
    const float* x    = (const float*)d_in[0];
    const float* Wih  = (const float*)d_in[1];
    const float* Whh  = (const float*)d_in[2];
    const float* bih  = (const float*)d_in[3];
    const float* bhh  = (const float*)d_in[4];
    const float* fcw  = (const float*)d_in[5];
    const float* fcb  = (const float*)d_in[6];
    float* out = (float*)d_out;

    char* ws = (char*)d_ws;
    uint32_t* qw4   = (uint32_t*)(ws + QW_OFF);
    uint32_t* wih4  = (uint32_t*)(ws + WIH_OFF);
    float*    s1v   = (float*)(ws + S1_OFF);
    float*    biasv = (float*)(ws + BIAS_OFF);
    uint32_t* xh    = (uint32_t*)(ws + XH_OFF);

    prep_w<<<1024, 64, 0, stream>>>(Whh, Wih, bih, bhh, qw4, wih4, s1v, biasv);
    prep_xh<<<(B_ * T_ * 16) / 256, 256, 0, stream>>>(x, xh);
    lstm_main<<<B_, 256, 0, stream>>>(qw4, wih4, s1v, biasv, xh, fcw, fcb, out);
}